// Round 18
// baseline (186.710 us; speedup 1.0000x reference)
//
#include <hip/hip_runtime.h>
#include <hip/hip_bf16.h>
#include <stdint.h>

typedef __attribute__((ext_vector_type(8))) short bf16x8;   // 8 bf16 = 4 VGPR
typedef __attribute__((ext_vector_type(4))) float f32x4;
typedef __attribute__((ext_vector_type(16))) float f32x16;  // 32x32 MFMA C/D
typedef __attribute__((ext_vector_type(2))) unsigned int u32x2;
typedef unsigned short u16;

#define DEVI static __device__ __forceinline__

DEVI u16 f2bf(float f) {  // RNE fp32 -> bf16
  union { float f; uint32_t u; } x; x.f = f;
  uint32_t r = (x.u + 0x7FFFu + ((x.u >> 16) & 1u)) >> 16;
  return (u16)r;
}

DEVI void gload_lds16(const void* g, void* lds) {
  __builtin_amdgcn_global_load_lds(
      (const __attribute__((address_space(1))) void*)(void*)g,
      (__attribute__((address_space(3))) void*)lds, 16, 0, 0);
}

// low 32 bits of a flat shared-pointer = LDS byte offset
DEVI unsigned ldsaddr(const void* p) { return (unsigned)(uintptr_t)p; }

// ---------------- fused fp32->bf16 converts + bias copies (1 dispatch) ----------------
__global__ void cvt_all_kernel(const float* __restrict__ x,
                               const float* __restrict__ Wq, const float* __restrict__ Wk,
                               const float* __restrict__ Wv, const float* __restrict__ Wo,
                               const float* __restrict__ bq, const float* __restrict__ bk,
                               const float* __restrict__ bv,
                               u16* __restrict__ xb, u16* __restrict__ Wqkvb,
                               u16* __restrict__ Wob, float* __restrict__ bqkv) {
  const int X4 = 2097152;          // x in float4 units (8192*1024/4)
  const int W4 = 262144;           // per-W float4 units (2^18)
  const int total = X4 + 4 * W4 + 768;
  int i = blockIdx.x * blockDim.x + threadIdx.x;
  const int stride = gridDim.x * blockDim.x;
  for (; i < total; i += stride) {
    if (i < X4) {
      float4 v = ((const float4*)x)[i];
      ((ushort4*)xb)[i] = make_ushort4(f2bf(v.x), f2bf(v.y), f2bf(v.z), f2bf(v.w));
    } else if (i < X4 + 4 * W4) {
      int j = i - X4;
      int which = j >> 18;
      int o = j & (W4 - 1);
      const float* src = which == 0 ? Wq : which == 1 ? Wk : which == 2 ? Wv : Wo;
      u16* dst = (which == 3) ? Wob : (Wqkvb + (size_t)which * 1048576);
      float4 v = ((const float4*)src)[o];
      ((ushort4*)dst)[o] = make_ushort4(f2bf(v.x), f2bf(v.y), f2bf(v.z), f2bf(v.w));
    } else {
      int j = i - X4 - 4 * W4;     // 0..767
      int which = j >> 8;
      int o = j & 255;
      const float* src = which == 0 ? bq : which == 1 ? bk : bv;
      ((float4*)bqkv)[which * 256 + o] = ((const float4*)src)[o];
    }
  }
}

// ---------------- GEMM: 128x128 tile, BK=32, 4 waves, 3-buffer counted prefetch --------
// C[M,N] = A[M,K] @ B[N,K]^T + bias (+col scale). Wave-tile 64x64 (2x2 waves).
// LDS 48KB = 3 bufs x 16KB -> 3 blocks/CU -> 12 waves/CU (vs 8 at the 512-thr config).
// Schedule (R8-proven): per tile vmcnt(4) [own 4 staged loads landed, tile t+1's 4 in
// flight]; s_barrier; STAGE(t+2); 8 ds_read_b128 (compiler-scheduled, unpinned);
// setprio(1); 16 MFMA; setprio(0). One barrier per K-tile; never drains in-loop.
// Rows are 64B stride -> inherent 2-way LDS access = free (m136), no swizzle needed.
template<int OUT_BF16>
__global__ __launch_bounds__(256, 2)
void gemm_s_kernel(const u16* __restrict__ A, const u16* __restrict__ B,
                   const float* __restrict__ bias, void* __restrict__ C,
                   int M, int N, int K, int scale_cols, float scale_val) {
  __shared__ u16 S[24576];   // 48KB: 3 bufs x [A 4096 u16 | B 4096 u16]
  const int tid = threadIdx.x;
  const int l = tid & 63;
  const int w = tid >> 6;
  const int wm = w >> 1, wn = w & 1;

  // XCD-aware remap: dispatch-linear -> tile-linear (chunked per XCD; nwg%8==0)
  const int lin = blockIdx.x + gridDim.x * blockIdx.y;
  const int per = (gridDim.x * gridDim.y) >> 3;
  const int nl = (lin & 7) * per + (lin >> 3);
  const int bn = nl % gridDim.x;
  const int bm = nl / gridDim.x;

  // staging: 4 x 16B per thread per tile. Rows tid>>2 (+64), chunk tid&3 covers BK=32.
  const u16* sA0 = A + (size_t)(bm * 128 + (tid >> 2)) * K + (tid & 3) * 8;
  const u16* sA1 = sA0 + (size_t)64 * K;
  const u16* sB0 = B + (size_t)(bn * 128 + (tid >> 2)) * K + (tid & 3) * 8;
  const u16* sB1 = sB0 + (size_t)64 * K;

#define SSTAGE(bufi, ko) { \
    gload_lds16(sA0 + (ko), &S[(bufi) * 8192 + tid * 8]); \
    gload_lds16(sA1 + (ko), &S[(bufi) * 8192 + 2048 + tid * 8]); \
    gload_lds16(sB0 + (ko), &S[(bufi) * 8192 + 4096 + tid * 8]); \
    gload_lds16(sB1 + (ko), &S[(bufi) * 8192 + 4096 + 2048 + tid * 8]); \
  }

  // frag read offsets (u16): row*32 + (l>>4)*8
  const int arow = (wm * 64 + (l & 15)) * 32 + (l >> 4) * 8;
  const int brow = 4096 + (wn * 64 + (l & 15)) * 32 + (l >> 4) * 8;

  f32x4 acc[4][4] = {};
  const int NT = K >> 5;   // K-tiles of 32

  SSTAGE(0, 0);
  SSTAGE(1, 32);

  int cur = 0;
  for (int t = 0; t < NT; ++t) {
    // own tile-t loads landed; tile t+1's 4 loads stay in flight
    if (t < NT - 1) { asm volatile("s_waitcnt vmcnt(4)" ::: "memory"); }
    else            { asm volatile("s_waitcnt vmcnt(0)" ::: "memory"); }
    __builtin_amdgcn_s_barrier();
    asm volatile("" ::: "memory");   // no LDS read hoisted above the barrier

    if (t < NT - 2) {
      int bs = cur + 2; if (bs >= 3) bs -= 3;
      SSTAGE(bs, (t + 2) * 32);      // depth-2 prefetch
    }

    const u16* sp = &S[cur * 8192];
    bf16x8 af[4], bf[4];
#pragma unroll
    for (int mf = 0; mf < 4; ++mf) af[mf] = *(const bf16x8*)&sp[arow + mf * 512];
#pragma unroll
    for (int nf = 0; nf < 4; ++nf) bf[nf] = *(const bf16x8*)&sp[brow + nf * 512];
    __builtin_amdgcn_s_setprio(1);
#pragma unroll
    for (int mf = 0; mf < 4; ++mf)
#pragma unroll
      for (int nf = 0; nf < 4; ++nf)
        acc[mf][nf] = __builtin_amdgcn_mfma_f32_16x16x32_bf16(af[mf], bf[nf], acc[mf][nf], 0, 0, 0);
    __builtin_amdgcn_s_setprio(0);

    asm volatile("" ::: "memory");   // keep this tile's reads above next barrier
    cur = (cur == 2) ? 0 : cur + 1;
  }

  // ---- epilogue (C/D layout m89-verified: col = l&15, row = (l>>4)*4 + j)
  const int rbase = bm * 128 + wm * 64 + (l >> 4) * 4;
  const int cbase = bn * 128 + wn * 64 + (l & 15);
#pragma unroll
  for (int nf = 0; nf < 4; ++nf) {
    int col = cbase + nf * 16;
    float bsv = bias[col];
    float sc = (col < scale_cols) ? scale_val : 1.0f;
#pragma unroll
    for (int mf = 0; mf < 4; ++mf) {
#pragma unroll
      for (int j = 0; j < 4; ++j) {
        int row = rbase + mf * 16 + j;
        float v = (acc[mf][nf][j] + bsv) * sc;
        if (OUT_BF16) ((u16*)C)[(size_t)row * N + col] = f2bf(v);
        else          ((float*)C)[(size_t)row * N + col] = v;
      }
    }
  }
#undef SSTAGE
}

// softmax + P->bf16 A-frag build for one group: exp2 in place, lane-local rowsum,
// cvt_pk pairs + single symmetric cross-half exchange (lane c <-> c+32).
DEVI void softmax_pa(f32x16& sA, f32x16& sB, bf16x8* pa, float& lsum, int hi) {
  float rs = 0.f;
#pragma unroll
  for (int r = 0; r < 16; ++r) { sA[r] = __builtin_amdgcn_exp2f(sA[r]); rs += sA[r]; }
#pragma unroll
  for (int r = 0; r < 16; ++r) { sB[r] = __builtin_amdgcn_exp2f(sB[r]); rs += sB[r]; }
  lsum += rs + __shfl_xor(rs, 32, 64);
#pragma unroll
  for (int i = 0; i < 4; ++i) {
    float p0 = (8 * i + 0 < 16) ? sA[(8 * i + 0) & 15] : sB[(8 * i + 0) & 15];
    float p1 = (8 * i + 1 < 16) ? sA[(8 * i + 1) & 15] : sB[(8 * i + 1) & 15];
    float p2 = (8 * i + 2 < 16) ? sA[(8 * i + 2) & 15] : sB[(8 * i + 2) & 15];
    float p3 = (8 * i + 3 < 16) ? sA[(8 * i + 3) & 15] : sB[(8 * i + 3) & 15];
    float p4 = (8 * i + 4 < 16) ? sA[(8 * i + 4) & 15] : sB[(8 * i + 4) & 15];
    float p5 = (8 * i + 5 < 16) ? sA[(8 * i + 5) & 15] : sB[(8 * i + 5) & 15];
    float p6 = (8 * i + 6 < 16) ? sA[(8 * i + 6) & 15] : sB[(8 * i + 6) & 15];
    float p7 = (8 * i + 7 < 16) ? sA[(8 * i + 7) & 15] : sB[(8 * i + 7) & 15];
    unsigned a0, a1, b0, b1;
    asm("v_cvt_pk_bf16_f32 %0, %1, %2" : "=v"(a0) : "v"(p0), "v"(p1));
    asm("v_cvt_pk_bf16_f32 %0, %1, %2" : "=v"(a1) : "v"(p2), "v"(p3));
    asm("v_cvt_pk_bf16_f32 %0, %1, %2" : "=v"(b0) : "v"(p4), "v"(p5));
    asm("v_cvt_pk_bf16_f32 %0, %1, %2" : "=v"(b1) : "v"(p6), "v"(p7));
    unsigned t0 = hi ? a0 : b0;   // each lane sends the pair its partner needs
    unsigned t1 = hi ? a1 : b1;
    unsigned x0 = (unsigned)__shfl_xor((int)t0, 32, 64);
    unsigned x1 = (unsigned)__shfl_xor((int)t1, 32, 64);
    union { unsigned u[4]; bf16x8 v; } U;
    U.u[0] = hi ? x0 : a0;   // keys base+0,1
    U.u[1] = hi ? x1 : a1;   // keys base+2,3
    U.u[2] = hi ? b0 : x0;   // keys base+4,5
    U.u[3] = hi ? b1 : x1;   // keys base+6,7
    pa[i] = U.v;
  }
}

// ---------------- flash attention (R15 exact — best measured: 89.1 us) -----------------
// Swapped-QK^T 32x32, max-free, 64 q-rows/wave, depth-2 counted prefetch, 3 buffers,
// XCD-aware block swizzle (FETCH 139 -> 24.7 MB verified).
__global__ __launch_bounds__(256, 2)
void attn_kernel(const u16* __restrict__ QKV, u16* __restrict__ O) {
  __shared__ u16 Ks[3][4096];  // [buf][64 key][64 d], blk-swizzled: phys = db ^ (key&7)
  __shared__ u16 Vs[3][4096];  // [buf] subtiled [key>>2][d>>4][key&3][d&15] for tr_b16

  const int tid = threadIdx.x;
  const int l = tid & 63, w = tid >> 6;
  const int hi = l >> 5, c = l & 31;
  // XCD-aware remap (bijective on [0,512)): same bh -> same lin%8 -> same XCD
  const int lin = blockIdx.x + 8 * blockIdx.y;
  const int bx = (lin >> 3) & 7;                    // q-block index [0,8)
  const int bh = (lin & 7) * 8 + (lin >> 6);        // (b,h) index [0,64)
  const int b = bh >> 4, h = bh & 15;
  const int qb = bx * 256 + w * 64;                 // 64 q-rows per wave
  const size_t rowbase = (size_t)b * 2048;

  bf16x8 qf0[4], qf1[4];
  {
    const u16* Qp0 = QKV + (rowbase + qb + c) * 3072 + h * 64 + hi * 8;
    const u16* Qp1 = QKV + (rowbase + qb + 32 + c) * 3072 + h * 64 + hi * 8;
#pragma unroll
    for (int kk = 0; kk < 4; ++kk) {
      qf0[kk] = *(const bf16x8*)(Qp0 + kk * 16);
      qf1[kk] = *(const bf16x8*)(Qp1 + kk * 16);
    }
  }

  const int kd0 = (w * 2 + 0) * 64 + l;
  const int kd1 = (w * 2 + 1) * 64 + l;
  const int rK0 = kd0 >> 3, dbK0 = (kd0 & 7) ^ (rK0 & 7);
  const int rK1 = kd1 >> 3, dbK1 = (kd1 & 7) ^ (rK1 & 7);
  const u16* srcK0 = QKV + (rowbase + rK0) * 3072 + 1024 + h * 64 + dbK0 * 8;
  const u16* srcK1 = QKV + (rowbase + rK1) * 3072 + 1024 + h * 64 + dbK1 * 8;
  const int kV0 = (kd0 >> 5) * 4 + ((kd0 >> 1) & 3), dV0 = ((kd0 >> 3) & 3) * 16 + (kd0 & 1) * 8;
  const int kV1 = (kd1 >> 5) * 4 + ((kd1 >> 1) & 3), dV1 = ((kd1 >> 3) & 3) * 16 + (kd1 & 1) * 8;
  const u16* srcV0 = QKV + (rowbase + kV0) * 3072 + 2048 + h * 64 + dV0;
  const u16* srcV1 = QKV + (rowbase + kV1) * 3072 + 2048 + h * 64 + dV1;

#define STAGE(buf, tile) { \
    const size_t koff = (size_t)(tile) * 64 * 3072; \
    gload_lds16(srcK0 + koff, &Ks[buf][(w * 2 + 0) * 512]); \
    gload_lds16(srcK1 + koff, &Ks[buf][(w * 2 + 1) * 512]); \
    gload_lds16(srcV0 + koff, &Vs[buf][(w * 2 + 0) * 512]); \
    gload_lds16(srcV1 + koff, &Vs[buf][(w * 2 + 1) * 512]); \
  }

  int koffs[4];
#pragma unroll
  for (int kk = 0; kk < 4; ++kk) koffs[kk] = (((kk * 2 + hi) ^ (c & 7)) * 8);
  const int kbase = c * 64;

  const unsigned vbase = ldsaddr(&Vs[0][0]) + (unsigned)(hi * 1024 + (c >> 4) * 128 + (c & 15) * 8);

  f32x16 o00 = {0,0,0,0,0,0,0,0,0,0,0,0,0,0,0,0};
  f32x16 o01 = {0,0,0,0,0,0,0,0,0,0,0,0,0,0,0,0};
  f32x16 o10 = {0,0,0,0,0,0,0,0,0,0,0,0,0,0,0,0};
  f32x16 o11 = {0,0,0,0,0,0,0,0,0,0,0,0,0,0,0,0};
  float lsum0 = 0.f, lsum1 = 0.f;

  STAGE(0, 0);
  STAGE(1, 1);

  int cur = 0;
  for (int t = 0; t < 32; ++t) {
    if (t < 31) { asm volatile("s_waitcnt vmcnt(4)" ::: "memory"); }
    else        { asm volatile("s_waitcnt vmcnt(0)" ::: "memory"); }
    __builtin_amdgcn_s_barrier();
    asm volatile("" ::: "memory");

    if (t < 30) {
      int bs = cur + 2; if (bs >= 3) bs -= 3;
      STAGE(bs, t + 2);
    }

    const u16* kp = &Ks[cur][0];
    bf16x8 kf[2][4];
#pragma unroll
    for (int kb = 0; kb < 2; ++kb)
#pragma unroll
      for (int kk = 0; kk < 4; ++kk)
        kf[kb][kk] = *(const bf16x8*)&kp[kbase + kb * 2048 + koffs[kk]];

    f32x16 sA0 = {0,0,0,0,0,0,0,0,0,0,0,0,0,0,0,0};
    f32x16 sB0 = {0,0,0,0,0,0,0,0,0,0,0,0,0,0,0,0};
    f32x16 sA1 = {0,0,0,0,0,0,0,0,0,0,0,0,0,0,0,0};
    f32x16 sB1 = {0,0,0,0,0,0,0,0,0,0,0,0,0,0,0,0};
#pragma unroll
    for (int kk = 0; kk < 4; ++kk) {
      sA0 = __builtin_amdgcn_mfma_f32_32x32x16_bf16(kf[0][kk], qf0[kk], sA0, 0, 0, 0);
      sB0 = __builtin_amdgcn_mfma_f32_32x32x16_bf16(kf[1][kk], qf0[kk], sB0, 0, 0, 0);
      sA1 = __builtin_amdgcn_mfma_f32_32x32x16_bf16(kf[0][kk], qf1[kk], sA1, 0, 0, 0);
      sB1 = __builtin_amdgcn_mfma_f32_32x32x16_bf16(kf[1][kk], qf1[kk], sB1, 0, 0, 0);
    }

    const unsigned va = vbase + (unsigned)(cur * 8192);
    u32x2 tt[4][4];
#pragma unroll
    for (int ks = 0; ks < 4; ++ks) {
      unsigned va_ks = va + (unsigned)(ks * 2048);
      asm volatile("ds_read_b64_tr_b16 %0, %1 offset:0"   : "=v"(tt[ks][0]) : "v"(va_ks));
      asm volatile("ds_read_b64_tr_b16 %0, %1 offset:512" : "=v"(tt[ks][1]) : "v"(va_ks));
      asm volatile("ds_read_b64_tr_b16 %0, %1 offset:256" : "=v"(tt[ks][2]) : "v"(va_ks));
      asm volatile("ds_read_b64_tr_b16 %0, %1 offset:768" : "=v"(tt[ks][3]) : "v"(va_ks));
    }

    bf16x8 pa0[4];
    softmax_pa(sA0, sB0, pa0, lsum0, hi);

    asm volatile("s_waitcnt lgkmcnt(0)" ::: "memory");
    __builtin_amdgcn_sched_barrier(0);   // rule 18: inline-asm tr_b16 reads need the pin

#pragma unroll
    for (int ks = 0; ks < 4; ++ks) {
      union { u32x2 d2[2]; bf16x8 v; } V0, V1;
      V0.d2[0] = tt[ks][0]; V0.d2[1] = tt[ks][1];
      V1.d2[0] = tt[ks][2]; V1.d2[1] = tt[ks][3];
      o00 = __builtin_amdgcn_mfma_f32_32x32x16_bf16(pa0[ks], V0.v, o00, 0, 0, 0);
      o01 = __builtin_amdgcn_mfma_f32_32x32x16_bf16(pa0[ks], V1.v, o01, 0, 0, 0);
    }

    bf16x8 pa1[4];
    softmax_pa(sA1, sB1, pa1, lsum1, hi);

#pragma unroll
    for (int ks = 0; ks < 4; ++ks) {
      union { u32x2 d2[2]; bf16x8 v; } V0, V1;
      V0.d2[0] = tt[ks][0]; V0.d2[1] = tt[ks][1];
      V1.d2[0] = tt[ks][2]; V1.d2[1] = tt[ks][3];
      o10 = __builtin_amdgcn_mfma_f32_32x32x16_bf16(pa1[ks], V0.v, o10, 0, 0, 0);
      o11 = __builtin_amdgcn_mfma_f32_32x32x16_bf16(pa1[ks], V1.v, o11, 0, 0, 0);
    }

    asm volatile("" ::: "memory");
    cur = (cur == 2) ? 0 : cur + 1;
  }

  u16* Op0 = O + (rowbase + qb) * 1024 + h * 64 + c;
  u16* Op1 = O + (rowbase + qb + 32) * 1024 + h * 64 + c;
#pragma unroll
  for (int r = 0; r < 16; ++r) {
    int q = (r & 3) + 8 * (r >> 2) + 4 * hi;
    float inv0 = 1.0f / __shfl(lsum0, q, 64);
    float inv1 = 1.0f / __shfl(lsum1, q, 64);
    Op0[(size_t)q * 1024]      = f2bf(o00[r] * inv0);
    Op0[(size_t)q * 1024 + 32] = f2bf(o01[r] * inv0);
    Op1[(size_t)q * 1024]      = f2bf(o10[r] * inv1);
    Op1[(size_t)q * 1024 + 32] = f2bf(o11[r] * inv1);
  }
#undef STAGE
}

extern "C" void kernel_launch(void* const* d_in, const int* in_sizes, int n_in,
                              void* d_out, int out_size, void* d_ws, size_t ws_size,
                              hipStream_t stream) {
  const float* x  = (const float*)d_in[0];
  const float* Wq = (const float*)d_in[1];
  const float* bq = (const float*)d_in[2];
  const float* Wk = (const float*)d_in[3];
  const float* bk = (const float*)d_in[4];
  const float* Wv = (const float*)d_in[5];
  const float* bv = (const float*)d_in[6];
  const float* Wo = (const float*)d_in[7];
  const float* bo = (const float*)d_in[8];
  float* out = (float*)d_out;

  char* ws = (char*)d_ws;
  u16*   xb    = (u16*)(ws);                  // 8192x1024 bf16
  u16*   Wqkvb = (u16*)(ws + 16777216);       // 3072x1024 bf16
  u16*   Wob   = (u16*)(ws + 23068672);       // 1024x1024 bf16
  float* bqkv  = (float*)(ws + 25165824);     // 3072 fp32
  u16*   QKV   = (u16*)(ws + 25178112);       // 8192x3072 bf16
  u16*   Oa    = (u16*)(ws + 75509760);       // 8192x1024 bf16

  cvt_all_kernel<<<2048, 256, 0, stream>>>(x, Wq, Wk, Wv, Wo, bq, bk, bv,
                                           xb, Wqkvb, Wob, bqkv);

  // QKV = x @ [Wq;Wk;Wv]^T + bias; Q cols scaled by log2e/8 (exp2-domain scores)
  gemm_s_kernel<1><<<dim3(24, 64), 256, 0, stream>>>(xb, Wqkvb, bqkv, QKV,
                                                     8192, 3072, 1024, 1024,
                                                     0.125f * 1.4426950408889634f);
  // flash attention (R15 exact)
  attn_kernel<<<dim3(8, 64), 256, 0, stream>>>(QKV, Oa);
  // out = Oa @ Wo^T + bo
  gemm_s_kernel<0><<<dim3(8, 64), 256, 0, stream>>>(Oa, Wob, bo, out,
                                                    8192, 1024, 1024, 0, 1.0f);
}

// Round 19
// 176.562 us; speedup vs baseline: 1.0575x; 1.0575x over previous
//
#include <hip/hip_runtime.h>
#include <hip/hip_bf16.h>
#include <stdint.h>

typedef __attribute__((ext_vector_type(8))) short bf16x8;   // 8 bf16 = 4 VGPR
typedef __attribute__((ext_vector_type(4))) float f32x4;
typedef __attribute__((ext_vector_type(16))) float f32x16;  // 32x32 MFMA C/D
typedef __attribute__((ext_vector_type(2))) unsigned int u32x2;
typedef unsigned short u16;

#define DEVI static __device__ __forceinline__

DEVI u16 f2bf(float f) {  // RNE fp32 -> bf16
  union { float f; uint32_t u; } x; x.f = f;
  uint32_t r = (x.u + 0x7FFFu + ((x.u >> 16) & 1u)) >> 16;
  return (u16)r;
}

DEVI void gload_lds16(const void* g, void* lds) {
  __builtin_amdgcn_global_load_lds(
      (const __attribute__((address_space(1))) void*)(void*)g,
      (__attribute__((address_space(3))) void*)lds, 16, 0, 0);
}

// low 32 bits of a flat shared-pointer = LDS byte offset
DEVI unsigned ldsaddr(const void* p) { return (unsigned)(uintptr_t)p; }

// ---------------- fused fp32->bf16 converts + bias copies (1 dispatch) ----------------
__global__ void cvt_all_kernel(const float* __restrict__ x,
                               const float* __restrict__ Wq, const float* __restrict__ Wk,
                               const float* __restrict__ Wv, const float* __restrict__ Wo,
                               const float* __restrict__ bq, const float* __restrict__ bk,
                               const float* __restrict__ bv,
                               u16* __restrict__ xb, u16* __restrict__ Wqkvb,
                               u16* __restrict__ Wob, float* __restrict__ bqkv) {
  const int X4 = 2097152;          // x in float4 units (8192*1024/4)
  const int W4 = 262144;           // per-W float4 units (2^18)
  const int total = X4 + 4 * W4 + 768;
  int i = blockIdx.x * blockDim.x + threadIdx.x;
  const int stride = gridDim.x * blockDim.x;
  for (; i < total; i += stride) {
    if (i < X4) {
      float4 v = ((const float4*)x)[i];
      ((ushort4*)xb)[i] = make_ushort4(f2bf(v.x), f2bf(v.y), f2bf(v.z), f2bf(v.w));
    } else if (i < X4 + 4 * W4) {
      int j = i - X4;
      int which = j >> 18;
      int o = j & (W4 - 1);
      const float* src = which == 0 ? Wq : which == 1 ? Wk : which == 2 ? Wv : Wo;
      u16* dst = (which == 3) ? Wob : (Wqkvb + (size_t)which * 1048576);
      float4 v = ((const float4*)src)[o];
      ((ushort4*)dst)[o] = make_ushort4(f2bf(v.x), f2bf(v.y), f2bf(v.z), f2bf(v.w));
    } else {
      int j = i - X4 - 4 * W4;     // 0..767
      int which = j >> 8;
      int o = j & 255;
      const float* src = which == 0 ? bq : which == 1 ? bk : bv;
      ((float4*)bqkv)[which * 256 + o] = ((const float4*)src)[o];
    }
  }
}

// ---------------- GEMM: 128x256 tile, BK=32, R8-style depth-2 counted prefetch ---------
// C[M,N] = A[M,K] @ B[N,K]^T + bias (+col scale). 8 waves (2M x 4N), wave-tile 64x64.
// LDS 72KB = 3 bufs x 24KB (A 8KB + B 16KB) -> 2 blocks/CU. R17 config — best measured
// (177.1 us total). R18's 128x128/48KB/3-blk variant regressed (reuse-bound, not TLP).
// Schedule: per tile vmcnt(3); s_barrier; STAGE(t+2); 8 ds_read_b128 (unpinned);
// setprio(1); 16 MFMA; setprio(0). One barrier per K-tile; never drains in-loop.
template<int OUT_BF16>
__global__ __launch_bounds__(512, 2)
void gemm_r8_kernel(const u16* __restrict__ A, const u16* __restrict__ B,
                    const float* __restrict__ bias, void* __restrict__ C,
                    int M, int N, int K, int scale_cols, float scale_val) {
  __shared__ u16 S[36864];   // 72KB: 3 bufs x [A 4096 u16 | B 8192 u16]
  const int tid = threadIdx.x;
  const int l = tid & 63;
  const int w = tid >> 6;
  const int wm = w >> 2, wn = w & 3;

  // XCD-aware remap: dispatch-linear -> tile-linear (chunked per XCD; nwg%8==0)
  const int lin = blockIdx.x + gridDim.x * blockIdx.y;
  const int per = (gridDim.x * gridDim.y) >> 3;
  const int nl = (lin & 7) * per + (lin >> 3);
  const int bn = nl % gridDim.x;
  const int bm = nl / gridDim.x;

  const u16* sA  = A + (size_t)(bm * 128 + (tid >> 2)) * K + (tid & 3) * 8;
  const u16* sB0 = B + (size_t)(bn * 256 + (tid >> 2)) * K + (tid & 3) * 8;
  const u16* sB1 = sB0 + (size_t)128 * K;

#define RSTAGE(bufi, ko) { \
    gload_lds16(sA  + (ko), &S[(bufi) * 12288 + tid * 8]); \
    gload_lds16(sB0 + (ko), &S[(bufi) * 12288 + 4096 + tid * 8]); \
    gload_lds16(sB1 + (ko), &S[(bufi) * 12288 + 4096 + 4096 + tid * 8]); \
  }

  // frag read offsets (u16): row*32 + (l>>4)*8
  const int arow = (wm * 64 + (l & 15)) * 32 + (l >> 4) * 8;
  const int brow = (wn * 64 + (l & 15)) * 32 + (l >> 4) * 8;

  f32x4 acc[4][4] = {};
  const int NT = K >> 5;   // K-tiles of 32

  RSTAGE(0, 0);
  RSTAGE(1, 32);

  int cur = 0;
  for (int t = 0; t < NT; ++t) {
    // own tile-t loads landed; tile t+1's 3 loads stay in flight
    if (t < NT - 1) { asm volatile("s_waitcnt vmcnt(3)" ::: "memory"); }
    else            { asm volatile("s_waitcnt vmcnt(0)" ::: "memory"); }
    __builtin_amdgcn_s_barrier();
    asm volatile("" ::: "memory");   // no LDS read hoisted above the barrier

    if (t < NT - 2) {
      int bs = cur + 2; if (bs >= 3) bs -= 3;
      RSTAGE(bs, (t + 2) * 32);      // depth-2 prefetch
    }

    const u16* ap = &S[cur * 12288];
    const u16* bp = &S[cur * 12288 + 4096];
    bf16x8 af[4], bf[4];
#pragma unroll
    for (int mf = 0; mf < 4; ++mf) af[mf] = *(const bf16x8*)&ap[arow + mf * 512];
#pragma unroll
    for (int nf = 0; nf < 4; ++nf) bf[nf] = *(const bf16x8*)&bp[brow + nf * 512];
    __builtin_amdgcn_s_setprio(1);
#pragma unroll
    for (int mf = 0; mf < 4; ++mf)
#pragma unroll
      for (int nf = 0; nf < 4; ++nf)
        acc[mf][nf] = __builtin_amdgcn_mfma_f32_16x16x32_bf16(af[mf], bf[nf], acc[mf][nf], 0, 0, 0);
    __builtin_amdgcn_s_setprio(0);

    asm volatile("" ::: "memory");   // keep this tile's reads above next barrier
    cur = (cur == 2) ? 0 : cur + 1;
  }

  // ---- epilogue (C/D layout m89-verified: col = l&15, row = (l>>4)*4 + j)
  const int rbase = bm * 128 + wm * 64 + (l >> 4) * 4;
  const int cbase = bn * 256 + wn * 64 + (l & 15);
#pragma unroll
  for (int nf = 0; nf < 4; ++nf) {
    int col = cbase + nf * 16;
    float bsv = bias[col];
    float sc = (col < scale_cols) ? scale_val : 1.0f;
#pragma unroll
    for (int mf = 0; mf < 4; ++mf) {
#pragma unroll
      for (int j = 0; j < 4; ++j) {
        int row = rbase + mf * 16 + j;
        float v = (acc[mf][nf][j] + bsv) * sc;
        if (OUT_BF16) ((u16*)C)[(size_t)row * N + col] = f2bf(v);
        else          ((float*)C)[(size_t)row * N + col] = v;
      }
    }
  }
#undef RSTAGE
}

// softmax + P->bf16 A-frag build for one group: exp2 in place, lane-local rowsum,
// cvt_pk pairs + single symmetric cross-half exchange (lane c <-> c+32).
DEVI void softmax_pa(f32x16& sA, f32x16& sB, bf16x8* pa, float& lsum, int hi) {
  float rs = 0.f;
#pragma unroll
  for (int r = 0; r < 16; ++r) { sA[r] = __builtin_amdgcn_exp2f(sA[r]); rs += sA[r]; }
#pragma unroll
  for (int r = 0; r < 16; ++r) { sB[r] = __builtin_amdgcn_exp2f(sB[r]); rs += sB[r]; }
  lsum += rs + __shfl_xor(rs, 32, 64);
#pragma unroll
  for (int i = 0; i < 4; ++i) {
    float p0 = (8 * i + 0 < 16) ? sA[(8 * i + 0) & 15] : sB[(8 * i + 0) & 15];
    float p1 = (8 * i + 1 < 16) ? sA[(8 * i + 1) & 15] : sB[(8 * i + 1) & 15];
    float p2 = (8 * i + 2 < 16) ? sA[(8 * i + 2) & 15] : sB[(8 * i + 2) & 15];
    float p3 = (8 * i + 3 < 16) ? sA[(8 * i + 3) & 15] : sB[(8 * i + 3) & 15];
    float p4 = (8 * i + 4 < 16) ? sA[(8 * i + 4) & 15] : sB[(8 * i + 4) & 15];
    float p5 = (8 * i + 5 < 16) ? sA[(8 * i + 5) & 15] : sB[(8 * i + 5) & 15];
    float p6 = (8 * i + 6 < 16) ? sA[(8 * i + 6) & 15] : sB[(8 * i + 6) & 15];
    float p7 = (8 * i + 7 < 16) ? sA[(8 * i + 7) & 15] : sB[(8 * i + 7) & 15];
    unsigned a0, a1, b0, b1;
    asm("v_cvt_pk_bf16_f32 %0, %1, %2" : "=v"(a0) : "v"(p0), "v"(p1));
    asm("v_cvt_pk_bf16_f32 %0, %1, %2" : "=v"(a1) : "v"(p2), "v"(p3));
    asm("v_cvt_pk_bf16_f32 %0, %1, %2" : "=v"(b0) : "v"(p4), "v"(p5));
    asm("v_cvt_pk_bf16_f32 %0, %1, %2" : "=v"(b1) : "v"(p6), "v"(p7));
    unsigned t0 = hi ? a0 : b0;   // each lane sends the pair its partner needs
    unsigned t1 = hi ? a1 : b1;
    unsigned x0 = (unsigned)__shfl_xor((int)t0, 32, 64);
    unsigned x1 = (unsigned)__shfl_xor((int)t1, 32, 64);
    union { unsigned u[4]; bf16x8 v; } U;
    U.u[0] = hi ? x0 : a0;   // keys base+0,1
    U.u[1] = hi ? x1 : a1;   // keys base+2,3
    U.u[2] = hi ? b0 : x0;   // keys base+4,5
    U.u[3] = hi ? b1 : x1;   // keys base+6,7
    pa[i] = U.v;
  }
}

// ---------------- flash attention (R15 exact — best measured: 89.1 us) -----------------
// Swapped-QK^T 32x32, max-free, 64 q-rows/wave, depth-2 counted prefetch, 3 buffers,
// XCD-aware block swizzle (FETCH 139 -> 24.7 MB verified).
__global__ __launch_bounds__(256, 2)
void attn_kernel(const u16* __restrict__ QKV, u16* __restrict__ O) {
  __shared__ u16 Ks[3][4096];  // [buf][64 key][64 d], blk-swizzled: phys = db ^ (key&7)
  __shared__ u16 Vs[3][4096];  // [buf] subtiled [key>>2][d>>4][key&3][d&15] for tr_b16

  const int tid = threadIdx.x;
  const int l = tid & 63, w = tid >> 6;
  const int hi = l >> 5, c = l & 31;
  // XCD-aware remap (bijective on [0,512)): same bh -> same lin%8 -> same XCD
  const int lin = blockIdx.x + 8 * blockIdx.y;
  const int bx = (lin >> 3) & 7;                    // q-block index [0,8)
  const int bh = (lin & 7) * 8 + (lin >> 6);        // (b,h) index [0,64)
  const int b = bh >> 4, h = bh & 15;
  const int qb = bx * 256 + w * 64;                 // 64 q-rows per wave
  const size_t rowbase = (size_t)b * 2048;

  bf16x8 qf0[4], qf1[4];
  {
    const u16* Qp0 = QKV + (rowbase + qb + c) * 3072 + h * 64 + hi * 8;
    const u16* Qp1 = QKV + (rowbase + qb + 32 + c) * 3072 + h * 64 + hi * 8;
#pragma unroll
    for (int kk = 0; kk < 4; ++kk) {
      qf0[kk] = *(const bf16x8*)(Qp0 + kk * 16);
      qf1[kk] = *(const bf16x8*)(Qp1 + kk * 16);
    }
  }

  const int kd0 = (w * 2 + 0) * 64 + l;
  const int kd1 = (w * 2 + 1) * 64 + l;
  const int rK0 = kd0 >> 3, dbK0 = (kd0 & 7) ^ (rK0 & 7);
  const int rK1 = kd1 >> 3, dbK1 = (kd1 & 7) ^ (rK1 & 7);
  const u16* srcK0 = QKV + (rowbase + rK0) * 3072 + 1024 + h * 64 + dbK0 * 8;
  const u16* srcK1 = QKV + (rowbase + rK1) * 3072 + 1024 + h * 64 + dbK1 * 8;
  const int kV0 = (kd0 >> 5) * 4 + ((kd0 >> 1) & 3), dV0 = ((kd0 >> 3) & 3) * 16 + (kd0 & 1) * 8;
  const int kV1 = (kd1 >> 5) * 4 + ((kd1 >> 1) & 3), dV1 = ((kd1 >> 3) & 3) * 16 + (kd1 & 1) * 8;
  const u16* srcV0 = QKV + (rowbase + kV0) * 3072 + 2048 + h * 64 + dV0;
  const u16* srcV1 = QKV + (rowbase + kV1) * 3072 + 2048 + h * 64 + dV1;

#define STAGE(buf, tile) { \
    const size_t koff = (size_t)(tile) * 64 * 3072; \
    gload_lds16(srcK0 + koff, &Ks[buf][(w * 2 + 0) * 512]); \
    gload_lds16(srcK1 + koff, &Ks[buf][(w * 2 + 1) * 512]); \
    gload_lds16(srcV0 + koff, &Vs[buf][(w * 2 + 0) * 512]); \
    gload_lds16(srcV1 + koff, &Vs[buf][(w * 2 + 1) * 512]); \
  }

  int koffs[4];
#pragma unroll
  for (int kk = 0; kk < 4; ++kk) koffs[kk] = (((kk * 2 + hi) ^ (c & 7)) * 8);
  const int kbase = c * 64;

  const unsigned vbase = ldsaddr(&Vs[0][0]) + (unsigned)(hi * 1024 + (c >> 4) * 128 + (c & 15) * 8);

  f32x16 o00 = {0,0,0,0,0,0,0,0,0,0,0,0,0,0,0,0};
  f32x16 o01 = {0,0,0,0,0,0,0,0,0,0,0,0,0,0,0,0};
  f32x16 o10 = {0,0,0,0,0,0,0,0,0,0,0,0,0,0,0,0};
  f32x16 o11 = {0,0,0,0,0,0,0,0,0,0,0,0,0,0,0,0};
  float lsum0 = 0.f, lsum1 = 0.f;

  STAGE(0, 0);
  STAGE(1, 1);

  int cur = 0;
  for (int t = 0; t < 32; ++t) {
    if (t < 31) { asm volatile("s_waitcnt vmcnt(4)" ::: "memory"); }
    else        { asm volatile("s_waitcnt vmcnt(0)" ::: "memory"); }
    __builtin_amdgcn_s_barrier();
    asm volatile("" ::: "memory");

    if (t < 30) {
      int bs = cur + 2; if (bs >= 3) bs -= 3;
      STAGE(bs, t + 2);
    }

    const u16* kp = &Ks[cur][0];
    bf16x8 kf[2][4];
#pragma unroll
    for (int kb = 0; kb < 2; ++kb)
#pragma unroll
      for (int kk = 0; kk < 4; ++kk)
        kf[kb][kk] = *(const bf16x8*)&kp[kbase + kb * 2048 + koffs[kk]];

    f32x16 sA0 = {0,0,0,0,0,0,0,0,0,0,0,0,0,0,0,0};
    f32x16 sB0 = {0,0,0,0,0,0,0,0,0,0,0,0,0,0,0,0};
    f32x16 sA1 = {0,0,0,0,0,0,0,0,0,0,0,0,0,0,0,0};
    f32x16 sB1 = {0,0,0,0,0,0,0,0,0,0,0,0,0,0,0,0};
#pragma unroll
    for (int kk = 0; kk < 4; ++kk) {
      sA0 = __builtin_amdgcn_mfma_f32_32x32x16_bf16(kf[0][kk], qf0[kk], sA0, 0, 0, 0);
      sB0 = __builtin_amdgcn_mfma_f32_32x32x16_bf16(kf[1][kk], qf0[kk], sB0, 0, 0, 0);
      sA1 = __builtin_amdgcn_mfma_f32_32x32x16_bf16(kf[0][kk], qf1[kk], sA1, 0, 0, 0);
      sB1 = __builtin_amdgcn_mfma_f32_32x32x16_bf16(kf[1][kk], qf1[kk], sB1, 0, 0, 0);
    }

    const unsigned va = vbase + (unsigned)(cur * 8192);
    u32x2 tt[4][4];
#pragma unroll
    for (int ks = 0; ks < 4; ++ks) {
      unsigned va_ks = va + (unsigned)(ks * 2048);
      asm volatile("ds_read_b64_tr_b16 %0, %1 offset:0"   : "=v"(tt[ks][0]) : "v"(va_ks));
      asm volatile("ds_read_b64_tr_b16 %0, %1 offset:512" : "=v"(tt[ks][1]) : "v"(va_ks));
      asm volatile("ds_read_b64_tr_b16 %0, %1 offset:256" : "=v"(tt[ks][2]) : "v"(va_ks));
      asm volatile("ds_read_b64_tr_b16 %0, %1 offset:768" : "=v"(tt[ks][3]) : "v"(va_ks));
    }

    bf16x8 pa0[4];
    softmax_pa(sA0, sB0, pa0, lsum0, hi);

    asm volatile("s_waitcnt lgkmcnt(0)" ::: "memory");
    __builtin_amdgcn_sched_barrier(0);   // rule 18: inline-asm tr_b16 reads need the pin

#pragma unroll
    for (int ks = 0; ks < 4; ++ks) {
      union { u32x2 d2[2]; bf16x8 v; } V0, V1;
      V0.d2[0] = tt[ks][0]; V0.d2[1] = tt[ks][1];
      V1.d2[0] = tt[ks][2]; V1.d2[1] = tt[ks][3];
      o00 = __builtin_amdgcn_mfma_f32_32x32x16_bf16(pa0[ks], V0.v, o00, 0, 0, 0);
      o01 = __builtin_amdgcn_mfma_f32_32x32x16_bf16(pa0[ks], V1.v, o01, 0, 0, 0);
    }

    bf16x8 pa1[4];
    softmax_pa(sA1, sB1, pa1, lsum1, hi);

#pragma unroll
    for (int ks = 0; ks < 4; ++ks) {
      union { u32x2 d2[2]; bf16x8 v; } V0, V1;
      V0.d2[0] = tt[ks][0]; V0.d2[1] = tt[ks][1];
      V1.d2[0] = tt[ks][2]; V1.d2[1] = tt[ks][3];
      o10 = __builtin_amdgcn_mfma_f32_32x32x16_bf16(pa1[ks], V0.v, o10, 0, 0, 0);
      o11 = __builtin_amdgcn_mfma_f32_32x32x16_bf16(pa1[ks], V1.v, o11, 0, 0, 0);
    }

    asm volatile("" ::: "memory");
    cur = (cur == 2) ? 0 : cur + 1;
  }

  u16* Op0 = O + (rowbase + qb) * 1024 + h * 64 + c;
  u16* Op1 = O + (rowbase + qb + 32) * 1024 + h * 64 + c;
#pragma unroll
  for (int r = 0; r < 16; ++r) {
    int q = (r & 3) + 8 * (r >> 2) + 4 * hi;
    float inv0 = 1.0f / __shfl(lsum0, q, 64);
    float inv1 = 1.0f / __shfl(lsum1, q, 64);
    Op0[(size_t)q * 1024]      = f2bf(o00[r] * inv0);
    Op0[(size_t)q * 1024 + 32] = f2bf(o01[r] * inv0);
    Op1[(size_t)q * 1024]      = f2bf(o10[r] * inv1);
    Op1[(size_t)q * 1024 + 32] = f2bf(o11[r] * inv1);
  }
#undef STAGE
}

extern "C" void kernel_launch(void* const* d_in, const int* in_sizes, int n_in,
                              void* d_out, int out_size, void* d_ws, size_t ws_size,
                              hipStream_t stream) {
  const float* x  = (const float*)d_in[0];
  const float* Wq = (const float*)d_in[1];
  const float* bq = (const float*)d_in[2];
  const float* Wk = (const float*)d_in[3];
  const float* bk = (const float*)d_in[4];
  const float* Wv = (const float*)d_in[5];
  const float* bv = (const float*)d_in[6];
  const float* Wo = (const float*)d_in[7];
  const float* bo = (const float*)d_in[8];
  float* out = (float*)d_out;

  char* ws = (char*)d_ws;
  u16*   xb    = (u16*)(ws);                  // 8192x1024 bf16
  u16*   Wqkvb = (u16*)(ws + 16777216);       // 3072x1024 bf16
  u16*   Wob   = (u16*)(ws + 23068672);       // 1024x1024 bf16
  float* bqkv  = (float*)(ws + 25165824);     // 3072 fp32
  u16*   QKV   = (u16*)(ws + 25178112);       // 8192x3072 bf16
  u16*   Oa    = (u16*)(ws + 75509760);       // 8192x1024 bf16

  cvt_all_kernel<<<2048, 256, 0, stream>>>(x, Wq, Wk, Wv, Wo, bq, bk, bv,
                                           xb, Wqkvb, Wob, bqkv);

  // QKV = x @ [Wq;Wk;Wv]^T + bias; Q cols scaled by log2e/8 (exp2-domain scores)
  gemm_r8_kernel<1><<<dim3(12, 64), 512, 0, stream>>>(xb, Wqkvb, bqkv, QKV,
                                                      8192, 3072, 1024, 1024,
                                                      0.125f * 1.4426950408889634f);
  // flash attention (R15 exact)
  attn_kernel<<<dim3(8, 64), 256, 0, stream>>>(QKV, Oa);
  // out = Oa @ Wo^T + bo
  gemm_r8_kernel<0><<<dim3(4, 64), 512, 0, stream>>>(Oa, Wob, bo, out,
                                                     8192, 1024, 1024, 0, 1.0f);
}